// Round 1
// baseline (2229.703 us; speedup 1.0000x reference)
//
#include <hip/hip_runtime.h>

#define BC 4096      // rows of hidden_current
#define BP 8192      // rows of hidden_previous
#define D  768
#define KNB 5
#define TOPK 6
#define NJ 4                 // j-chunks for the topk GEMM
#define JCH (BP / NJ)        // 2048 cols per chunk
#define TI 32                // rows per block
#define TJ 64                // cols per j-tile
#define BK 32                // k-chunk

// ---------------- normalize: y = x / max(||x||,eps); optional sq = ||y||^2 --------
__global__ __launch_bounds__(256) void k_norm(const float* __restrict__ x,
                                              float* __restrict__ y,
                                              float* __restrict__ sqout) {
    int row = blockIdx.x;
    int t = threadIdx.x;
    const float* xr = x + (size_t)row * D;
    float v0 = xr[t], v1 = xr[t + 256], v2 = xr[t + 512];
    float s = v0 * v0 + v1 * v1 + v2 * v2;
    #pragma unroll
    for (int off = 32; off; off >>= 1) s += __shfl_xor(s, off, 64);
    __shared__ float wsum[4];
    if ((t & 63) == 0) wsum[t >> 6] = s;
    __syncthreads();
    float tot = wsum[0] + wsum[1] + wsum[2] + wsum[3];
    float rinv = 1.0f / fmaxf(sqrtf(tot), 1e-12f);
    float* yr = y + (size_t)row * D;
    yr[t] = v0 * rinv; yr[t + 256] = v1 * rinv; yr[t + 512] = v2 * rinv;
    if (sqout != nullptr && t == 0) sqout[row] = tot * rinv * rinv;
}

// ---------------- fused similarity GEMM + per-row running top-6 ----------------
// block: 256 thr. rows r0..r0+31 (i<4096), cols c0..c0+JCH-1. Writes per-chunk top-6.
__global__ __launch_bounds__(256) void k_sim_topk(const float* __restrict__ hpn,
                                                  float* __restrict__ topv,
                                                  int* __restrict__ topi) {
    __shared__ float sA[TI * 36];       // [row][k], stride 36 (16B-aligned f4 rows)
    __shared__ float sBt[BK * 73];      // [k][col], stride 73 (conflict-free reads)
    __shared__ float sS[TI * 65];       // score tile dump
    __shared__ float tv[TI * TOPK];
    __shared__ int   tidx[TI * TOPK];

    int t  = threadIdx.x;
    int tx = t & 63;          // col within tile
    int ty = t >> 6;          // row group (0..3), rows ty*8..ty*8+7
    int r0 = blockIdx.x * TI;
    int c0 = blockIdx.y * JCH;

    if (t < TI * TOPK) { tv[t] = -1e30f; tidx[t] = 0x7fffffff; }

    int arow = t >> 3, acol = (t & 7) * 4;   // A staging: 4 floats/thread
    int brow = t >> 2, bcol = (t & 3) * 8;   // B staging: 8 floats/thread
    const float* Ag = hpn + (size_t)(r0 + arow) * D + acol;

    for (int jt = 0; jt < JCH; jt += TJ) {
        float acc[8];
        #pragma unroll
        for (int r = 0; r < 8; r++) acc[r] = 0.f;
        const float* Bg = hpn + (size_t)(c0 + jt + brow) * D + bcol;

        for (int kk = 0; kk < D; kk += BK) {
            __syncthreads();
            float4 a4  = *(const float4*)(Ag + kk);
            float4 b4a = *(const float4*)(Bg + kk);
            float4 b4b = *(const float4*)(Bg + kk + 4);
            *(float4*)&sA[arow * 36 + acol] = a4;
            // transposed store: sBt[k][col]
            sBt[(bcol + 0) * 73 + brow] = b4a.x;
            sBt[(bcol + 1) * 73 + brow] = b4a.y;
            sBt[(bcol + 2) * 73 + brow] = b4a.z;
            sBt[(bcol + 3) * 73 + brow] = b4a.w;
            sBt[(bcol + 4) * 73 + brow] = b4b.x;
            sBt[(bcol + 5) * 73 + brow] = b4b.y;
            sBt[(bcol + 6) * 73 + brow] = b4b.z;
            sBt[(bcol + 7) * 73 + brow] = b4b.w;
            __syncthreads();
            #pragma unroll
            for (int k4 = 0; k4 < BK; k4 += 4) {
                float4 a[8];
                #pragma unroll
                for (int r = 0; r < 8; r++)
                    a[r] = *(const float4*)&sA[(ty * 8 + r) * 36 + k4];  // broadcast
                #pragma unroll
                for (int i = 0; i < 4; i++) {
                    float bv = sBt[(k4 + i) * 73 + tx];
                    #pragma unroll
                    for (int r = 0; r < 8; r++) {
                        float av = (i == 0) ? a[r].x : (i == 1) ? a[r].y
                                 : (i == 2) ? a[r].z : a[r].w;
                        acc[r] += av * bv;
                    }
                }
            }
        }
        // dump tile and scan (1 lane per row, wave 0 lanes 0..31)
        #pragma unroll
        for (int r = 0; r < 8; r++) sS[(ty * 8 + r) * 65 + tx] = acc[r];
        __syncthreads();
        if (t < TI) {
            float thr = tv[t * TOPK + 5];
            for (int c = 0; c < TJ; c++) {
                float v = sS[t * 65 + c];
                if (v > thr) {
                    int j = c0 + jt + c;
                    int s;
                    for (s = 0; s < TOPK; s++) if (v > tv[t * TOPK + s]) break;
                    for (int q = TOPK - 1; q > s; q--) {
                        tv[t * TOPK + q]   = tv[t * TOPK + q - 1];
                        tidx[t * TOPK + q] = tidx[t * TOPK + q - 1];
                    }
                    tv[t * TOPK + s] = v; tidx[t * TOPK + s] = j;
                    thr = tv[t * TOPK + 5];
                }
            }
        }
        __syncthreads();
    }
    if (t < TI * TOPK) {
        int row = r0 + t / TOPK, slot = t % TOPK;
        size_t o = ((size_t)row * NJ + blockIdx.y) * TOPK + slot;
        topv[o] = tv[t];
        topi[o] = tidx[t];
    }
}

// ---------------- merge per-chunk top-6 lists -> final 5 neighbors ----------------
__global__ __launch_bounds__(256) void k_merge(const float* __restrict__ topv,
                                               const int* __restrict__ topi,
                                               int* __restrict__ nbr) {
    int row = blockIdx.x * 256 + threadIdx.x;
    if (row >= BC) return;
    float bv[TOPK]; int bi[TOPK];
    #pragma unroll
    for (int s = 0; s < TOPK; s++) { bv[s] = -1e30f; bi[s] = 0x7fffffff; }
    for (int ch = 0; ch < NJ; ch++) {
        for (int s0 = 0; s0 < TOPK; s0++) {
            size_t o = ((size_t)row * NJ + ch) * TOPK + s0;
            float v = topv[o];
            if (v > bv[TOPK - 1]) {
                int j = topi[o];
                int s;
                for (s = 0; s < TOPK; s++) if (v > bv[s]) break;
                for (int q = TOPK - 1; q > s; q--) { bv[q] = bv[q - 1]; bi[q] = bi[q - 1]; }
                bv[s] = v; bi[s] = j;
            }
        }
    }
    // rank 0 is self (similarity ~= 1.0); keep ranks 1..5
    #pragma unroll
    for (int s = 0; s < KNB; s++) nbr[row * KNB + s] = bi[s + 1];
}

// ---------------- sparse loss: sum over (i, nbr) pairs with j < BC ----------------
__global__ __launch_bounds__(64) void k_loss(const float* __restrict__ hcn,
                                             const float* __restrict__ sq,
                                             const int* __restrict__ nbr,
                                             const int* __restrict__ labp,
                                             float* __restrict__ partial) {
    int i = blockIdx.x;
    int lane = threadIdx.x;
    const float* hi = hcn + (size_t)i * D;
    float part = 0.f;
    int li = labp[i];
    for (int s = 0; s < KNB; s++) {
        int j = nbr[i * KNB + s];
        if (j >= BC) continue;
        const float* hj = hcn + (size_t)j * D;
        float d = 0.f;
        #pragma unroll
        for (int m = 0; m < D / 64; m++) d += hi[lane + 64 * m] * hj[lane + 64 * m];
        #pragma unroll
        for (int off = 32; off; off >>= 1) d += __shfl_xor(d, off, 64);
        float d2 = fmaxf(sq[i] + sq[j] - 2.0f * d, 0.0f);
        float e = (li == labp[j]) ? 1.0f : -1.0f;
        part += e * d2;
    }
    if (lane == 0) partial[i] = part;
}

// ---------------- final reduce + scale ----------------
__global__ __launch_bounds__(256) void k_final(const float* __restrict__ partial,
                                               float* __restrict__ out) {
    __shared__ float red[256];
    int t = threadIdx.x;
    float s = 0.f;
    for (int i = t; i < BC; i += 256) s += partial[i];
    red[t] = s;
    __syncthreads();
    for (int off = 128; off; off >>= 1) {
        if (t < off) red[t] += red[t + off];
        __syncthreads();
    }
    if (t == 0) out[0] = 0.5f * red[0] / ((float)BC * (float)BC);
}

extern "C" void kernel_launch(void* const* d_in, const int* in_sizes, int n_in,
                              void* d_out, int out_size, void* d_ws, size_t ws_size,
                              hipStream_t stream) {
    const float* hc   = (const float*)d_in[0];  // hidden_current  (4096,768)
    const float* hp   = (const float*)d_in[1];  // hidden_previous (8192,768)
    const int*   labp = (const int*)d_in[3];    // labels_previous (8192,)
    float* out = (float*)d_out;

    // workspace layout
    float* ws   = (float*)d_ws;
    float* hpn  = ws;                                 // BP*D
    float* hcn  = hpn + (size_t)BP * D;               // BC*D
    float* sq   = hcn + (size_t)BC * D;               // BC
    float* topv = sq + BC;                            // BC*NJ*TOPK
    int*   topi = (int*)(topv + (size_t)BC * NJ * TOPK);
    int*   nbr  = topi + (size_t)BC * NJ * TOPK;      // BC*KNB
    float* partial = (float*)(nbr + (size_t)BC * KNB);// BC

    k_norm<<<dim3(BP), dim3(256), 0, stream>>>(hp, hpn, nullptr);
    k_norm<<<dim3(BC), dim3(256), 0, stream>>>(hc, hcn, sq);
    k_sim_topk<<<dim3(BC / TI, NJ), dim3(256), 0, stream>>>(hpn, topv, topi);
    k_merge<<<dim3(BC / 256), dim3(256), 0, stream>>>(topv, topi, nbr);
    k_loss<<<dim3(BC), dim3(64), 0, stream>>>(hcn, sq, nbr, labp, partial);
    k_final<<<dim3(1), dim3(256), 0, stream>>>(partial, out);
}

// Round 2
// 764.673 us; speedup vs baseline: 2.9159x; 2.9159x over previous
//
#include <hip/hip_runtime.h>

#define BC 4096      // rows of hidden_current
#define BP 8192      // rows of hidden_previous
#define D  768
#define KNB 5
#define TOPK 6
#define NT (BP / 128)   // 64 column tiles of the similarity matrix

typedef __bf16 bf16x8 __attribute__((ext_vector_type(8)));
typedef float  f32x4  __attribute__((ext_vector_type(4)));

__device__ __forceinline__ unsigned short f2bf(float f) {
    unsigned int u = __float_as_uint(f);
    u += 0x7fffu + ((u >> 16) & 1u);          // round-to-nearest-even
    return (unsigned short)(u >> 16);
}

__device__ __forceinline__ void gload16(const void* g, void* l) {
    __builtin_amdgcn_global_load_lds(
        (const __attribute__((address_space(1))) unsigned int*)g,
        (__attribute__((address_space(3))) unsigned int*)l, 16, 0, 0);
}

// ---------------- normalize hp -> bf16 (used only for similarity ranking) -------
__global__ __launch_bounds__(256) void k_norm_bf16(const float* __restrict__ x,
                                                   unsigned short* __restrict__ y) {
    int row = blockIdx.x;
    int t = threadIdx.x;
    const float* xr = x + (size_t)row * D;
    float v0 = xr[t], v1 = xr[t + 256], v2 = xr[t + 512];
    float s = v0 * v0 + v1 * v1 + v2 * v2;
    #pragma unroll
    for (int off = 32; off; off >>= 1) s += __shfl_xor(s, off, 64);
    __shared__ float wsum[4];
    if ((t & 63) == 0) wsum[t >> 6] = s;
    __syncthreads();
    float tot = wsum[0] + wsum[1] + wsum[2] + wsum[3];
    float rinv = 1.0f / fmaxf(sqrtf(tot), 1e-12f);
    unsigned short* yr = y + (size_t)row * D;
    yr[t] = f2bf(v0 * rinv); yr[t + 256] = f2bf(v1 * rinv); yr[t + 512] = f2bf(v2 * rinv);
}

// ---------------- normalize hc -> fp32 + squared norm (loss path, exact) --------
__global__ __launch_bounds__(256) void k_norm_f32(const float* __restrict__ x,
                                                  float* __restrict__ y,
                                                  float* __restrict__ sqout) {
    int row = blockIdx.x;
    int t = threadIdx.x;
    const float* xr = x + (size_t)row * D;
    float v0 = xr[t], v1 = xr[t + 256], v2 = xr[t + 512];
    float s = v0 * v0 + v1 * v1 + v2 * v2;
    #pragma unroll
    for (int off = 32; off; off >>= 1) s += __shfl_xor(s, off, 64);
    __shared__ float wsum[4];
    if ((t & 63) == 0) wsum[t >> 6] = s;
    __syncthreads();
    float tot = wsum[0] + wsum[1] + wsum[2] + wsum[3];
    float rinv = 1.0f / fmaxf(sqrtf(tot), 1e-12f);
    float* yr = y + (size_t)row * D;
    yr[t] = v0 * rinv; yr[t + 256] = v1 * rinv; yr[t + 512] = v2 * rinv;
    if (t == 0) sqout[row] = tot * rinv * rinv;
}

// ---------------- bf16 MFMA similarity tile + fused per-row top-6 ----------------
// grid (32, 64): 128x128 tile of S = hp_bf16[0:4096] . hp_bf16^T
__global__ __launch_bounds__(256) void k_simtop(const unsigned short* __restrict__ hp,
                                                float* __restrict__ candv,
                                                int* __restrict__ candi) {
    __shared__ char smem[32768];
    unsigned short* sA = (unsigned short*)smem;   // 128 rows x 64 k (bf16), chunk-swizzled
    unsigned short* sB = sA + 128 * 64;
    float* sS = (float*)smem;                     // 128 x 33 score buffer (aliased)

    const int t = threadIdx.x, w = t >> 6, l = t & 63;
    const int l15 = l & 15, quad = l >> 4;
    const int wr = w >> 1, wc = w & 1;
    const int ri = blockIdx.x, ci = blockIdx.y;

    // staging: lane handles row l>>3 of its 8-row group; XOR-swizzled 16B k-chunk
    const int srow = l >> 3;
    const int sch  = (l & 7) ^ srow;              // source k-chunk (0..7)
    const unsigned short* Ab = hp + (size_t)(ri * 128) * D;
    const unsigned short* Bb = hp + (size_t)(ci * 128) * D;

    f32x4 acc[4][4];
    #pragma unroll
    for (int i = 0; i < 4; i++)
        #pragma unroll
        for (int j = 0; j < 4; j++) acc[i][j] = (f32x4){0.f, 0.f, 0.f, 0.f};

    // fragment LDS chunk offsets (lane-constant; m&7 == l15&7 for all frags)
    const int x7  = l15 & 7;
    const int ch0 = (quad ^ x7) * 16;             // bytes, k-slab 0
    const int ch1 = ((quad + 4) ^ x7) * 16;       // bytes, k-slab 1

    for (int kk = 0; kk < D; kk += 64) {
        __syncthreads();
        #pragma unroll
        for (int p = 0; p < 4; p++) {
            int r = w * 32 + p * 8 + srow;
            gload16(Ab + (size_t)r * D + kk + sch * 8, sA + (w * 32 + p * 8) * 64);
            gload16(Bb + (size_t)r * D + kk + sch * 8, sB + (w * 32 + p * 8) * 64);
        }
        __syncthreads();
        #pragma unroll
        for (int ks = 0; ks < 2; ks++) {
            const int ch = ks ? ch1 : ch0;
            bf16x8 af[4], bf[4];
            #pragma unroll
            for (int mi = 0; mi < 4; mi++)
                af[mi] = *(const bf16x8*)((const char*)sA + (wr * 64 + mi * 16 + l15) * 128 + ch);
            #pragma unroll
            for (int ni = 0; ni < 4; ni++)
                bf[ni] = *(const bf16x8*)((const char*)sB + (wc * 64 + ni * 16 + l15) * 128 + ch);
            #pragma unroll
            for (int mi = 0; mi < 4; mi++)
                #pragma unroll
                for (int ni = 0; ni < 4; ni++)
                    acc[mi][ni] = __builtin_amdgcn_mfma_f32_16x16x32_bf16(af[mi], bf[ni], acc[mi][ni], 0, 0, 0);
        }
    }

    // fused epilogue: per-row top-6 over this 128x128 tile, in 4 chunks of 32 cols
    float bv[TOPK]; int bj[TOPK];
    #pragma unroll
    for (int s = 0; s < TOPK; s++) { bv[s] = -1e30f; bj[s] = 0x7fffffff; }

    for (int h = 0; h < 4; h++) {
        __syncthreads();                          // previous chunk scanned / K-loop reads done
        if (wc == (h >> 1)) {
            int ni0 = (h & 1) * 2;
            #pragma unroll
            for (int mi = 0; mi < 4; mi++)
                #pragma unroll
                for (int n2 = 0; n2 < 2; n2++) {
                    int c  = n2 * 16 + l15;
                    int rb = wr * 64 + mi * 16 + quad * 4;
                    f32x4 v = acc[mi][ni0 + n2];
                    #pragma unroll
                    for (int r = 0; r < 4; r++) sS[(rb + r) * 33 + c] = v[r];
                }
        }
        __syncthreads();
        if (t < 128) {
            int jbase = ci * 128 + h * 32;
            for (int c = 0; c < 32; c++) {
                float v = sS[t * 33 + c];
                if (v > bv[TOPK - 1]) {
                    int s;
                    for (s = 0; s < TOPK; s++) if (v > bv[s]) break;
                    for (int q = TOPK - 1; q > s; q--) { bv[q] = bv[q - 1]; bj[q] = bj[q - 1]; }
                    bv[s] = v; bj[s] = jbase + c;
                }
            }
        }
    }
    if (t < 128) {
        size_t o = ((size_t)(ri * 128 + t) * NT + ci) * TOPK;
        #pragma unroll
        for (int s = 0; s < TOPK; s++) { candv[o + s] = bv[s]; candi[o + s] = bj[s]; }
    }
}

// ---------------- merge 64 per-tile top-6 lists -> final 5 neighbors -------------
__global__ __launch_bounds__(256) void k_merge(const float* __restrict__ candv,
                                               const int* __restrict__ candi,
                                               int* __restrict__ nbr) {
    int row = blockIdx.x * 256 + threadIdx.x;
    if (row >= BC) return;
    float bv[TOPK]; int bj[TOPK];
    #pragma unroll
    for (int s = 0; s < TOPK; s++) { bv[s] = -1e30f; bj[s] = 0x7fffffff; }
    const float* cv = candv + (size_t)row * NT * TOPK;
    const int*   cj = candi + (size_t)row * NT * TOPK;
    for (int q0 = 0; q0 < NT * TOPK; q0++) {
        float v = cv[q0];
        if (v > bv[TOPK - 1]) {
            int j = cj[q0];
            int s;
            for (s = 0; s < TOPK; s++) if (v > bv[s]) break;
            for (int q = TOPK - 1; q > s; q--) { bv[q] = bv[q - 1]; bj[q] = bj[q - 1]; }
            bv[s] = v; bj[s] = j;
        }
    }
    // rank 0 is self (sim ~= 1.0 >> cross-sims); keep ranks 1..5
    #pragma unroll
    for (int s = 0; s < KNB; s++) nbr[row * KNB + s] = bj[s + 1];
}

// ---------------- sparse loss over (i, nbr) pairs with j < BC, exact fp32 --------
__global__ __launch_bounds__(64) void k_loss(const float* __restrict__ hcn,
                                             const float* __restrict__ sq,
                                             const int* __restrict__ nbr,
                                             const int* __restrict__ labp,
                                             float* __restrict__ partial) {
    int i = blockIdx.x;
    int lane = threadIdx.x;
    const float* hi = hcn + (size_t)i * D;
    float part = 0.f;
    int li = labp[i];
    for (int s = 0; s < KNB; s++) {
        int j = nbr[i * KNB + s];
        if (j >= BC) continue;
        const float* hj = hcn + (size_t)j * D;
        float d = 0.f;
        #pragma unroll
        for (int m = 0; m < D / 64; m++) d += hi[lane + 64 * m] * hj[lane + 64 * m];
        #pragma unroll
        for (int off = 32; off; off >>= 1) d += __shfl_xor(d, off, 64);
        float d2 = fmaxf(sq[i] + sq[j] - 2.0f * d, 0.0f);
        float e = (li == labp[j]) ? 1.0f : -1.0f;
        part += e * d2;
    }
    if (lane == 0) partial[i] = part;
}

__global__ __launch_bounds__(256) void k_final(const float* __restrict__ partial,
                                               float* __restrict__ out) {
    __shared__ float red[256];
    int t = threadIdx.x;
    float s = 0.f;
    for (int i = t; i < BC; i += 256) s += partial[i];
    red[t] = s;
    __syncthreads();
    for (int off = 128; off; off >>= 1) {
        if (t < off) red[t] += red[t + off];
        __syncthreads();
    }
    if (t == 0) out[0] = 0.5f * red[0] / ((float)BC * (float)BC);
}

extern "C" void kernel_launch(void* const* d_in, const int* in_sizes, int n_in,
                              void* d_out, int out_size, void* d_ws, size_t ws_size,
                              hipStream_t stream) {
    const float* hc   = (const float*)d_in[0];  // hidden_current  (4096,768)
    const float* hp   = (const float*)d_in[1];  // hidden_previous (8192,768)
    const int*   labp = (const int*)d_in[3];    // labels_previous (8192,)
    float* out = (float*)d_out;

    // workspace layout (~37.9 MB)
    unsigned short* hpnb = (unsigned short*)d_ws;          // BP*D bf16
    float* hcn  = (float*)(hpnb + (size_t)BP * D);         // BC*D f32
    float* sq   = hcn + (size_t)BC * D;                    // BC
    float* candv = sq + BC;                                // BC*NT*TOPK
    int*   candi = (int*)(candv + (size_t)BC * NT * TOPK); // BC*NT*TOPK
    int*   nbr  = candi + (size_t)BC * NT * TOPK;          // BC*KNB
    float* partial = (float*)(nbr + (size_t)BC * KNB);     // BC

    k_norm_bf16<<<dim3(BP), dim3(256), 0, stream>>>(hp, hpnb);
    k_norm_f32<<<dim3(BC), dim3(256), 0, stream>>>(hc, hcn, sq);
    k_simtop<<<dim3(BC / 128, NT), dim3(256), 0, stream>>>(hpnb, candv, candi);
    k_merge<<<dim3(BC / 256), dim3(256), 0, stream>>>(candv, candi, nbr);
    k_loss<<<dim3(BC), dim3(64), 0, stream>>>(hcn, sq, nbr, labp, partial);
    k_final<<<dim3(1), dim3(256), 0, stream>>>(partial, out);
}

// Round 3
// 465.373 us; speedup vs baseline: 4.7912x; 1.6431x over previous
//
#include <hip/hip_runtime.h>

#define BC 4096      // rows of hidden_current
#define BP 8192      // rows of hidden_previous
#define D  768
#define KNB 5
#define TOPK 6
#define NT (BP / 128)   // 64 column tiles of the similarity matrix

typedef __bf16 bf16x8 __attribute__((ext_vector_type(8)));
typedef float  f32x4  __attribute__((ext_vector_type(4)));

__device__ __forceinline__ unsigned short f2bf(float f) {
    unsigned int u = __float_as_uint(f);
    u += 0x7fffu + ((u >> 16) & 1u);          // round-to-nearest-even
    return (unsigned short)(u >> 16);
}

__device__ __forceinline__ void topk_insert(float v, int j, float* bv, int* bj) {
    int s;
    #pragma unroll
    for (s = 0; s < TOPK; s++) if (v > bv[s]) break;
    #pragma unroll
    for (int q = TOPK - 1; q > 0; q--) {
        if (q > s) { bv[q] = bv[q - 1]; bj[q] = bj[q - 1]; }
    }
    if (s < TOPK) { bv[s] = v; bj[s] = j; }
}

// ---------------- normalize hp -> bf16 (similarity-ranking path only) -----------
__global__ __launch_bounds__(256) void k_norm_bf16(const float* __restrict__ x,
                                                   unsigned short* __restrict__ y) {
    int row = blockIdx.x;
    int t = threadIdx.x;
    const float* xr = x + (size_t)row * D;
    float v0 = xr[t], v1 = xr[t + 256], v2 = xr[t + 512];
    float s = v0 * v0 + v1 * v1 + v2 * v2;
    #pragma unroll
    for (int off = 32; off; off >>= 1) s += __shfl_xor(s, off, 64);
    __shared__ float wsum[4];
    if ((t & 63) == 0) wsum[t >> 6] = s;
    __syncthreads();
    float tot = wsum[0] + wsum[1] + wsum[2] + wsum[3];
    float rinv = 1.0f / fmaxf(sqrtf(tot), 1e-12f);
    unsigned short* yr = y + (size_t)row * D;
    yr[t] = f2bf(v0 * rinv); yr[t + 256] = f2bf(v1 * rinv); yr[t + 512] = f2bf(v2 * rinv);
}

// ---------------- normalize hc -> fp32 + squared norm (loss path, exact) --------
__global__ __launch_bounds__(256) void k_norm_f32(const float* __restrict__ x,
                                                  float* __restrict__ y,
                                                  float* __restrict__ sqout) {
    int row = blockIdx.x;
    int t = threadIdx.x;
    const float* xr = x + (size_t)row * D;
    float v0 = xr[t], v1 = xr[t + 256], v2 = xr[t + 512];
    float s = v0 * v0 + v1 * v1 + v2 * v2;
    #pragma unroll
    for (int off = 32; off; off >>= 1) s += __shfl_xor(s, off, 64);
    __shared__ float wsum[4];
    if ((t & 63) == 0) wsum[t >> 6] = s;
    __syncthreads();
    float tot = wsum[0] + wsum[1] + wsum[2] + wsum[3];
    float rinv = 1.0f / fmaxf(sqrtf(tot), 1e-12f);
    float* yr = y + (size_t)row * D;
    yr[t] = v0 * rinv; yr[t + 256] = v1 * rinv; yr[t + 512] = v2 * rinv;
    if (t == 0) sqout[row] = tot * rinv * rinv;
}

// ---------------- bf16 MFMA similarity tile + fused per-row top-6 ----------------
// grid (32, 64): 128x128 tile of S = hp_bf16[0:4096] . hp_bf16^T
// Staging: monotone global_load_dwordx4 -> regs -> XOR-swizzled ds_write_b128.
__global__ __launch_bounds__(256) void k_simtop(const unsigned short* __restrict__ hp,
                                                float* __restrict__ candv,
                                                int* __restrict__ candi) {
    __shared__ char smem[39424];
    unsigned short* sA = (unsigned short*)smem;          // [128 rows][64 k] swizzled
    unsigned short* sB = sA + 128 * 64;
    float* sS = (float*)smem;                            // [128][65] score buffer (alias)
    float* mv = (float*)(smem + 33280);                  // [128][6] partner top-6 vals
    int*   mj = (int*)(smem + 33280 + 3072);             // [128][6] partner top-6 idx

    const int t = threadIdx.x;
    const int l = t & 63;
    const int w = t >> 6;
    const int l15 = l & 15, quad = l >> 4;
    const int wr = w >> 1, wc = w & 1;
    const int ri = blockIdx.x, ci = blockIdx.y;

    const unsigned short* Ab = hp + (size_t)(ri * 128) * D;
    const unsigned short* Bb = hp + (size_t)(ci * 128) * D;

    // staging assignment: chunk c = p*256 + t  (p=0..3): row=c>>3, src chunk=c&7
    // global read is monotone in lane; LDS write position is (c&7)^(row&7) [XOR swizzle]
    const unsigned short* pa[4];
    const unsigned short* pb[4];
    int wofs[4];                                         // swizzled LDS byte offset
    #pragma unroll
    for (int p = 0; p < 4; p++) {
        int c = p * 256 + t;
        int row = c >> 3, pos = c & 7;
        pa[p] = Ab + (size_t)row * D + pos * 8;
        pb[p] = Bb + (size_t)row * D + pos * 8;
        wofs[p] = row * 128 + ((pos ^ (row & 7)) * 16);
    }

    float4 ra[4], rb[4];
    #pragma unroll
    for (int p = 0; p < 4; p++) { ra[p] = *(const float4*)pa[p]; rb[p] = *(const float4*)pb[p]; }

    f32x4 acc[4][4];
    #pragma unroll
    for (int i = 0; i < 4; i++)
        #pragma unroll
        for (int j = 0; j < 4; j++) acc[i][j] = (f32x4){0.f, 0.f, 0.f, 0.f};

    // fragment LDS chunk offsets (lane-constant): source chunk q lives at pos q^(row&7)
    const int x7  = l15 & 7;
    const int ch0 = (quad ^ x7) * 16;
    const int ch1 = ((quad + 4) ^ x7) * 16;

    for (int kk = 0; kk < D; kk += 64) {
        __syncthreads();                                 // LDS readers of prev iter done
        #pragma unroll
        for (int p = 0; p < 4; p++) {
            *(float4*)(smem + wofs[p]) = ra[p];                       // sA region
            *(float4*)(smem + 128 * 128 + wofs[p]) = rb[p];           // sB region
        }
        __syncthreads();                                 // tile ready
        int kn = kk + 64;
        if (kn < D) {
            #pragma unroll
            for (int p = 0; p < 4; p++) {
                ra[p] = *(const float4*)(pa[p] + kn);
                rb[p] = *(const float4*)(pb[p] + kn);
            }
        }
        #pragma unroll
        for (int ks = 0; ks < 2; ks++) {
            const int ch = ks ? ch1 : ch0;
            bf16x8 af[4], bfr[4];
            #pragma unroll
            for (int mi = 0; mi < 4; mi++)
                af[mi] = *(const bf16x8*)((const char*)sA + (wr * 64 + mi * 16 + l15) * 128 + ch);
            #pragma unroll
            for (int ni = 0; ni < 4; ni++)
                bfr[ni] = *(const bf16x8*)((const char*)sB + (wc * 64 + ni * 16 + l15) * 128 + ch);
            #pragma unroll
            for (int mi = 0; mi < 4; mi++)
                #pragma unroll
                for (int ni = 0; ni < 4; ni++)
                    acc[mi][ni] = __builtin_amdgcn_mfma_f32_16x16x32_bf16(af[mi], bfr[ni], acc[mi][ni], 0, 0, 0);
        }
    }

    // epilogue: 2 dump phases of 64 cols; 256 threads scan 2-per-row (32 cols each)
    float bv[TOPK]; int bj[TOPK];
    #pragma unroll
    for (int s = 0; s < TOPK; s++) { bv[s] = -1e30f; bj[s] = 0x7fffffff; }

    const int srow = t & 127, scb = (t >> 7) * 32;
    #pragma unroll
    for (int h = 0; h < 2; h++) {
        __syncthreads();                                 // prior LDS reads done
        if (wc == h) {
            #pragma unroll
            for (int mi = 0; mi < 4; mi++)
                #pragma unroll
                for (int ni = 0; ni < 4; ni++) {
                    int colb = ni * 16 + l15;
                    int rowb = wr * 64 + mi * 16 + quad * 4;
                    f32x4 v = acc[mi][ni];
                    #pragma unroll
                    for (int r = 0; r < 4; r++) sS[(rowb + r) * 65 + colb] = v[r];
                }
        }
        __syncthreads();
        int jbase = ci * 128 + h * 64 + scb;
        for (int c = 0; c < 32; c++) {
            float v = sS[srow * 65 + scb + c];
            if (v > bv[TOPK - 1]) topk_insert(v, jbase + c, bv, bj);
        }
    }

    // merge the two half-row scanners
    __syncthreads();
    if (t >= 128) {
        #pragma unroll
        for (int s = 0; s < TOPK; s++) { mv[(t - 128) * TOPK + s] = bv[s]; mj[(t - 128) * TOPK + s] = bj[s]; }
    }
    __syncthreads();
    if (t < 128) {
        #pragma unroll
        for (int s0 = 0; s0 < TOPK; s0++) {
            float v = mv[t * TOPK + s0];
            if (v > bv[TOPK - 1]) topk_insert(v, mj[t * TOPK + s0], bv, bj);
        }
        size_t o = ((size_t)(ri * 128 + t) * NT + ci) * TOPK;
        #pragma unroll
        for (int s = 0; s < TOPK; s++) { candv[o + s] = bv[s]; candi[o + s] = bj[s]; }
    }
}

// ---------------- merge 64 per-tile top-6 lists -> final 5 neighbors -------------
__global__ __launch_bounds__(256) void k_merge(const float* __restrict__ candv,
                                               const int* __restrict__ candi,
                                               int* __restrict__ nbr) {
    int row = blockIdx.x * 256 + threadIdx.x;
    if (row >= BC) return;
    float bv[TOPK]; int bj[TOPK];
    #pragma unroll
    for (int s = 0; s < TOPK; s++) { bv[s] = -1e30f; bj[s] = 0x7fffffff; }
    const float* cv = candv + (size_t)row * NT * TOPK;
    const int*   cj = candi + (size_t)row * NT * TOPK;
    for (int q0 = 0; q0 < NT * TOPK; q0++) {
        float v = cv[q0];
        if (v > bv[TOPK - 1]) topk_insert(v, cj[q0], bv, bj);
    }
    // rank 0 is self (sim ~= 1.0 >> cross-sims); keep ranks 1..5
    #pragma unroll
    for (int s = 0; s < KNB; s++) nbr[row * KNB + s] = bj[s + 1];
}

// ---------------- sparse loss over (i, nbr) pairs with j < BC, exact fp32 --------
__global__ __launch_bounds__(64) void k_loss(const float* __restrict__ hcn,
                                             const float* __restrict__ sq,
                                             const int* __restrict__ nbr,
                                             const int* __restrict__ labp,
                                             float* __restrict__ partial) {
    int i = blockIdx.x;
    int lane = threadIdx.x;
    const float* hi = hcn + (size_t)i * D;
    float part = 0.f;
    int li = labp[i];
    for (int s = 0; s < KNB; s++) {
        int j = nbr[i * KNB + s];
        if (j >= BC) continue;
        const float* hj = hcn + (size_t)j * D;
        float d = 0.f;
        #pragma unroll
        for (int m = 0; m < D / 64; m++) d += hi[lane + 64 * m] * hj[lane + 64 * m];
        #pragma unroll
        for (int off = 32; off; off >>= 1) d += __shfl_xor(d, off, 64);
        float d2 = fmaxf(sq[i] + sq[j] - 2.0f * d, 0.0f);
        float e = (li == labp[j]) ? 1.0f : -1.0f;
        part += e * d2;
    }
    if (lane == 0) partial[i] = part;
}

__global__ __launch_bounds__(256) void k_final(const float* __restrict__ partial,
                                               float* __restrict__ out) {
    __shared__ float red[256];
    int t = threadIdx.x;
    float s = 0.f;
    for (int i = t; i < BC; i += 256) s += partial[i];
    red[t] = s;
    __syncthreads();
    for (int off = 128; off; off >>= 1) {
        if (t < off) red[t] += red[t + off];
        __syncthreads();
    }
    if (t == 0) out[0] = 0.5f * red[0] / ((float)BC * (float)BC);
}

extern "C" void kernel_launch(void* const* d_in, const int* in_sizes, int n_in,
                              void* d_out, int out_size, void* d_ws, size_t ws_size,
                              hipStream_t stream) {
    const float* hc   = (const float*)d_in[0];  // hidden_current  (4096,768)
    const float* hp   = (const float*)d_in[1];  // hidden_previous (8192,768)
    const int*   labp = (const int*)d_in[3];    // labels_previous (8192,)
    float* out = (float*)d_out;

    // workspace layout (~38 MB)
    unsigned short* hpnb = (unsigned short*)d_ws;          // BP*D bf16
    float* hcn  = (float*)(hpnb + (size_t)BP * D);         // BC*D f32
    float* sq   = hcn + (size_t)BC * D;                    // BC
    float* candv = sq + BC;                                // BC*NT*TOPK
    int*   candi = (int*)(candv + (size_t)BC * NT * TOPK); // BC*NT*TOPK
    int*   nbr  = candi + (size_t)BC * NT * TOPK;          // BC*KNB
    float* partial = (float*)(nbr + (size_t)BC * KNB);     // BC

    k_norm_bf16<<<dim3(BP), dim3(256), 0, stream>>>(hp, hpnb);
    k_norm_f32<<<dim3(BC), dim3(256), 0, stream>>>(hc, hcn, sq);
    k_simtop<<<dim3(BC / 128, NT), dim3(256), 0, stream>>>(hpnb, candv, candi);
    k_merge<<<dim3(BC / 256), dim3(256), 0, stream>>>(candv, candi, nbr);
    k_loss<<<dim3(BC), dim3(64), 0, stream>>>(hcn, sq, nbr, labp, partial);
    k_final<<<dim3(1), dim3(256), 0, stream>>>(partial, out);
}

// Round 4
// 389.660 us; speedup vs baseline: 5.7222x; 1.1943x over previous
//
#include <hip/hip_runtime.h>

#define BC 4096      // rows of hidden_current
#define BP 8192      // rows of hidden_previous
#define D  768
#define KNB 5
#define TOPK 6
#define NT (BP / 128)   // 64 column tiles of the similarity matrix

typedef __bf16 bf16x8 __attribute__((ext_vector_type(8)));
typedef float  f32x4  __attribute__((ext_vector_type(4)));

__device__ __forceinline__ unsigned short f2bf(float f) {
    unsigned int u = __float_as_uint(f);
    u += 0x7fffu + ((u >> 16) & 1u);          // round-to-nearest-even
    return (unsigned short)(u >> 16);
}

// strict-> insert: on ties the incumbent (earlier j) wins
__device__ __forceinline__ void topk_insert(float v, int j, float* bv, int* bj) {
    int s;
    #pragma unroll
    for (s = 0; s < TOPK; s++) if (v > bv[s]) break;
    #pragma unroll
    for (int q = TOPK - 1; q > 0; q--) {
        if (q > s) { bv[q] = bv[q - 1]; bj[q] = bj[q - 1]; }
    }
    if (s < TOPK) { bv[s] = v; bj[s] = j; }
}

// ---------------- fused normalize: hp -> bf16 ranking copy, hc -> fp32 + sq ------
__global__ __launch_bounds__(256) void k_norm(const float* __restrict__ hp,
                                              const float* __restrict__ hc,
                                              unsigned short* __restrict__ hpnb,
                                              float* __restrict__ hcn,
                                              float* __restrict__ sqout) {
    int b = blockIdx.x;
    int t = threadIdx.x;
    bool isP = (b < BP);
    int row = isP ? b : (b - BP);
    const float* xr = (isP ? hp : hc) + (size_t)row * D;
    float v0 = xr[t], v1 = xr[t + 256], v2 = xr[t + 512];
    float s = v0 * v0 + v1 * v1 + v2 * v2;
    #pragma unroll
    for (int off = 32; off; off >>= 1) s += __shfl_xor(s, off, 64);
    __shared__ float wsum[4];
    if ((t & 63) == 0) wsum[t >> 6] = s;
    __syncthreads();
    float tot = wsum[0] + wsum[1] + wsum[2] + wsum[3];
    float rinv = 1.0f / fmaxf(sqrtf(tot), 1e-12f);
    if (isP) {
        unsigned short* yr = hpnb + (size_t)row * D;
        yr[t] = f2bf(v0 * rinv); yr[t + 256] = f2bf(v1 * rinv); yr[t + 512] = f2bf(v2 * rinv);
    } else {
        float* yr = hcn + (size_t)row * D;
        yr[t] = v0 * rinv; yr[t + 256] = v1 * rinv; yr[t + 512] = v2 * rinv;
        if (t == 0) sqout[row] = tot * rinv * rinv;
    }
}

// ---------------- bf16 MFMA similarity tile + fused per-row top-6 ----------------
// grid (32, 64): 128x128 tile of S = hp_bf16[0:4096] . hp_bf16^T
// Staging: monotone global_load_dwordx4 -> regs -> XOR-swizzled ds_write_b128.
// __launch_bounds__(256,2): 256-reg budget -> NO scratch spill (round-3 lesson:
// bare (256) capped at 68 VGPR and spilled the prefetch regs -> 620 MB/launch).
__global__ __launch_bounds__(256, 2) void k_simtop(const unsigned short* __restrict__ hp,
                                                   float* __restrict__ candv,
                                                   int* __restrict__ candi) {
    __shared__ char smem[39424];
    unsigned short* sA = (unsigned short*)smem;          // [128 rows][64 k] swizzled
    unsigned short* sB = sA + 128 * 64;
    float* sS = (float*)smem;                            // [128][65] score buffer (alias)
    float* mv = (float*)(smem + 33280);                  // [128][6] partner top-6 vals
    int*   mj = (int*)(smem + 33280 + 3072);             // [128][6] partner top-6 idx

    const int t = threadIdx.x;
    const int l = t & 63;
    const int w = t >> 6;
    const int l15 = l & 15, quad = l >> 4;
    const int wr = w >> 1, wc = w & 1;
    const int ri = blockIdx.x, ci = blockIdx.y;

    const unsigned short* Ab = hp + (size_t)(ri * 128) * D;
    const unsigned short* Bb = hp + (size_t)(ci * 128) * D;

    // staging: chunk c = p*256 + t (p=0..3): row=c>>3, src chunk=c&7
    // global read monotone in lane; LDS write position (c&7)^(row&7) [XOR swizzle]
    const unsigned short* pa[4];
    const unsigned short* pb[4];
    int wofs[4];                                         // swizzled LDS byte offset
    #pragma unroll
    for (int p = 0; p < 4; p++) {
        int c = p * 256 + t;
        int row = c >> 3, pos = c & 7;
        pa[p] = Ab + (size_t)row * D + pos * 8;
        pb[p] = Bb + (size_t)row * D + pos * 8;
        wofs[p] = row * 128 + ((pos ^ (row & 7)) * 16);
    }

    float4 ra[4], rb[4];
    #pragma unroll
    for (int p = 0; p < 4; p++) { ra[p] = *(const float4*)pa[p]; rb[p] = *(const float4*)pb[p]; }

    f32x4 acc[4][4];
    #pragma unroll
    for (int i = 0; i < 4; i++)
        #pragma unroll
        for (int j = 0; j < 4; j++) acc[i][j] = (f32x4){0.f, 0.f, 0.f, 0.f};

    // fragment LDS chunk offsets (lane-constant): source chunk q sits at pos q^(row&7)
    const int x7  = l15 & 7;
    const int ch0 = (quad ^ x7) * 16;
    const int ch1 = ((quad + 4) ^ x7) * 16;

    for (int kk = 0; kk < D; kk += 64) {
        __syncthreads();                                 // LDS readers of prev iter done
        #pragma unroll
        for (int p = 0; p < 4; p++) {
            *(float4*)(smem + wofs[p]) = ra[p];                       // sA region
            *(float4*)(smem + 128 * 128 + wofs[p]) = rb[p];           // sB region
        }
        __syncthreads();                                 // tile ready
        int kn = kk + 64;
        if (kn < D) {
            #pragma unroll
            for (int p = 0; p < 4; p++) {
                ra[p] = *(const float4*)(pa[p] + kn);
                rb[p] = *(const float4*)(pb[p] + kn);
            }
        }
        #pragma unroll
        for (int ks = 0; ks < 2; ks++) {
            const int ch = ks ? ch1 : ch0;
            bf16x8 af[4], bfr[4];
            #pragma unroll
            for (int mi = 0; mi < 4; mi++)
                af[mi] = *(const bf16x8*)((const char*)sA + (wr * 64 + mi * 16 + l15) * 128 + ch);
            #pragma unroll
            for (int ni = 0; ni < 4; ni++)
                bfr[ni] = *(const bf16x8*)((const char*)sB + (wc * 64 + ni * 16 + l15) * 128 + ch);
            #pragma unroll
            for (int mi = 0; mi < 4; mi++)
                #pragma unroll
                for (int ni = 0; ni < 4; ni++)
                    acc[mi][ni] = __builtin_amdgcn_mfma_f32_16x16x32_bf16(af[mi], bfr[ni], acc[mi][ni], 0, 0, 0);
        }
    }

    // epilogue: 2 dump phases of 64 cols; 256 threads scan 2-per-row (32 cols each)
    float bv[TOPK]; int bj[TOPK];
    #pragma unroll
    for (int s = 0; s < TOPK; s++) { bv[s] = -1e30f; bj[s] = 0x7fffffff; }

    const int srow = t & 127, scb = (t >> 7) * 32;
    #pragma unroll
    for (int h = 0; h < 2; h++) {
        __syncthreads();                                 // prior LDS reads done
        if (wc == h) {
            #pragma unroll
            for (int mi = 0; mi < 4; mi++)
                #pragma unroll
                for (int ni = 0; ni < 4; ni++) {
                    int colb = ni * 16 + l15;
                    int rowb = wr * 64 + mi * 16 + quad * 4;
                    f32x4 v = acc[mi][ni];
                    #pragma unroll
                    for (int r = 0; r < 4; r++) sS[(rowb + r) * 65 + colb] = v[r];
                }
        }
        __syncthreads();
        int jbase = ci * 128 + h * 64 + scb;
        for (int c = 0; c < 32; c++) {
            float v = sS[srow * 65 + scb + c];
            if (v > bv[TOPK - 1]) topk_insert(v, jbase + c, bv, bj);
        }
    }

    // merge the two half-row scanners
    __syncthreads();
    if (t >= 128) {
        #pragma unroll
        for (int s = 0; s < TOPK; s++) { mv[(t - 128) * TOPK + s] = bv[s]; mj[(t - 128) * TOPK + s] = bj[s]; }
    }
    __syncthreads();
    if (t < 128) {
        #pragma unroll
        for (int s0 = 0; s0 < TOPK; s0++) {
            float v = mv[t * TOPK + s0];
            if (v > bv[TOPK - 1]) topk_insert(v, mj[t * TOPK + s0], bv, bj);
        }
        size_t o = ((size_t)(ri * 128 + t) * NT + ci) * TOPK;
        #pragma unroll
        for (int s = 0; s < TOPK; s++) { candv[o + s] = bv[s]; candi[o + s] = bj[s]; }
    }
}

// ------- fused merge (wave-parallel) + sparse loss. One 64-thread block per row --
// lane = tile index: lane's 6 candidates are that tile's sorted top-6.
// 6 xor-merge rounds; low-lane list is the insertion base so ties keep smaller j
// (matches sequential j-ascending scan semantics of the reference top_k).
__global__ __launch_bounds__(64) void k_mergeloss(const float* __restrict__ candv,
                                                  const int* __restrict__ candi,
                                                  const float* __restrict__ hcn,
                                                  const float* __restrict__ sq,
                                                  const int* __restrict__ labp,
                                                  float* __restrict__ partial) {
    int i = blockIdx.x;
    int lane = threadIdx.x;
    const float* cv = candv + ((size_t)i * NT + lane) * TOPK;
    const int*   cj = candi + ((size_t)i * NT + lane) * TOPK;
    float bv[TOPK]; int bj[TOPK];
    #pragma unroll
    for (int s = 0; s < TOPK; s++) { bv[s] = cv[s]; bj[s] = cj[s]; }

    #pragma unroll
    for (int off = 1; off < 64; off <<= 1) {
        float pv[TOPK]; int pj[TOPK];
        #pragma unroll
        for (int s = 0; s < TOPK; s++) {
            pv[s] = __shfl_xor(bv[s], off, 64);
            pj[s] = __shfl_xor(bj[s], off, 64);
        }
        bool ilow = (lane & off) == 0;
        float av[TOPK], iv[TOPK]; int aj[TOPK], ij[TOPK];
        #pragma unroll
        for (int s = 0; s < TOPK; s++) {
            av[s] = ilow ? bv[s] : pv[s];  aj[s] = ilow ? bj[s] : pj[s];
            iv[s] = ilow ? pv[s] : bv[s];  ij[s] = ilow ? pj[s] : bj[s];
        }
        #pragma unroll
        for (int s = 0; s < TOPK; s++)
            if (iv[s] > av[TOPK - 1]) topk_insert(iv[s], ij[s], av, aj);
        #pragma unroll
        for (int s = 0; s < TOPK; s++) { bv[s] = av[s]; bj[s] = aj[s]; }
    }

    // all lanes now hold the row's global top-6; rank 0 is self -> use ranks 1..5
    const float* hi = hcn + (size_t)i * D;
    float part = 0.f;
    int li = labp[i];
    #pragma unroll
    for (int s = 1; s <= KNB; s++) {
        int j = bj[s];
        if (j >= BC) continue;
        const float* hj = hcn + (size_t)j * D;
        float d = 0.f;
        #pragma unroll
        for (int m = 0; m < D / 64; m++) d += hi[lane + 64 * m] * hj[lane + 64 * m];
        #pragma unroll
        for (int off = 32; off; off >>= 1) d += __shfl_xor(d, off, 64);
        float d2 = fmaxf(sq[i] + sq[j] - 2.0f * d, 0.0f);
        float e = (li == labp[j]) ? 1.0f : -1.0f;
        part += e * d2;
    }
    if (lane == 0) partial[i] = part;
}

__global__ __launch_bounds__(256) void k_final(const float* __restrict__ partial,
                                               float* __restrict__ out) {
    __shared__ float red[256];
    int t = threadIdx.x;
    float s = 0.f;
    for (int i = t; i < BC; i += 256) s += partial[i];
    red[t] = s;
    __syncthreads();
    for (int off = 128; off; off >>= 1) {
        if (t < off) red[t] += red[t + off];
        __syncthreads();
    }
    if (t == 0) out[0] = 0.5f * red[0] / ((float)BC * (float)BC);
}

extern "C" void kernel_launch(void* const* d_in, const int* in_sizes, int n_in,
                              void* d_out, int out_size, void* d_ws, size_t ws_size,
                              hipStream_t stream) {
    const float* hc   = (const float*)d_in[0];  // hidden_current  (4096,768)
    const float* hp   = (const float*)d_in[1];  // hidden_previous (8192,768)
    const int*   labp = (const int*)d_in[3];    // labels_previous (8192,)
    float* out = (float*)d_out;

    // workspace layout (~38 MB)
    unsigned short* hpnb = (unsigned short*)d_ws;          // BP*D bf16
    float* hcn  = (float*)(hpnb + (size_t)BP * D);         // BC*D f32
    float* sq   = hcn + (size_t)BC * D;                    // BC
    float* candv = sq + BC;                                // BC*NT*TOPK
    int*   candi = (int*)(candv + (size_t)BC * NT * TOPK); // BC*NT*TOPK
    float* partial = (float*)(candi + (size_t)BC * NT * TOPK); // BC

    k_norm<<<dim3(BP + BC), dim3(256), 0, stream>>>(hp, hc, hpnb, hcn, sq);
    k_simtop<<<dim3(BC / 128, NT), dim3(256), 0, stream>>>(hpnb, candv, candi);
    k_mergeloss<<<dim3(BC), dim3(64), 0, stream>>>(candv, candi, hcn, sq, labp, partial);
    k_final<<<dim3(1), dim3(256), 0, stream>>>(partial, out);
}

// Round 5
// 370.878 us; speedup vs baseline: 6.0120x; 1.0506x over previous
//
#include <hip/hip_runtime.h>

#define BC 4096      // rows of hidden_current
#define BP 8192      // rows of hidden_previous
#define D  768
#define KNB 5
#define TOPK 6
#define NT (BP / 128)   // 64 column tiles of the similarity matrix

typedef __bf16 bf16x8 __attribute__((ext_vector_type(8)));
typedef float  f32x4  __attribute__((ext_vector_type(4)));

__device__ __forceinline__ unsigned short f2bf(float f) {
    unsigned int u = __float_as_uint(f);
    u += 0x7fffu + ((u >> 16) & 1u);          // round-to-nearest-even
    return (unsigned short)(u >> 16);
}

// Branchless insertion network, STATIC indices only (runtime-indexed private
// stores put the arrays in scratch -> 790 MB/launch of scratch traffic, r3/r4
// lesson). Strict >: on ties the incumbent (earlier j) wins, matching the
// reference's sequential j-ascending top_k semantics.
__device__ __forceinline__ void topk_insert(float v, int j, float* bv, int* bj) {
    #pragma unroll
    for (int q = TOPK - 1; q >= 1; q--) {
        bool up   = v > bv[q - 1];                 // v belongs at q-1 or above: shift
        bool here = (v > bv[q]) && !up;            // v lands exactly at slot q
        bv[q] = up ? bv[q - 1] : (here ? v : bv[q]);
        bj[q] = up ? bj[q - 1] : (here ? j : bj[q]);
    }
    if (v > bv[0]) { bv[0] = v; bj[0] = j; }
}

// ---------------- fused normalize: hp -> bf16 ranking copy, hc -> fp32 + sq ------
__global__ __launch_bounds__(256) void k_norm(const float* __restrict__ hp,
                                              const float* __restrict__ hc,
                                              unsigned short* __restrict__ hpnb,
                                              float* __restrict__ hcn,
                                              float* __restrict__ sqout) {
    int b = blockIdx.x;
    int t = threadIdx.x;
    bool isP = (b < BP);
    int row = isP ? b : (b - BP);
    const float* xr = (isP ? hp : hc) + (size_t)row * D;
    float v0 = xr[t], v1 = xr[t + 256], v2 = xr[t + 512];
    float s = v0 * v0 + v1 * v1 + v2 * v2;
    #pragma unroll
    for (int off = 32; off; off >>= 1) s += __shfl_xor(s, off, 64);
    __shared__ float wsum[4];
    if ((t & 63) == 0) wsum[t >> 6] = s;
    __syncthreads();
    float tot = wsum[0] + wsum[1] + wsum[2] + wsum[3];
    float rinv = 1.0f / fmaxf(sqrtf(tot), 1e-12f);
    if (isP) {
        unsigned short* yr = hpnb + (size_t)row * D;
        yr[t] = f2bf(v0 * rinv); yr[t + 256] = f2bf(v1 * rinv); yr[t + 512] = f2bf(v2 * rinv);
    } else {
        float* yr = hcn + (size_t)row * D;
        yr[t] = v0 * rinv; yr[t + 256] = v1 * rinv; yr[t + 512] = v2 * rinv;
        if (t == 0) sqout[row] = tot * rinv * rinv;
    }
}

// ---------------- bf16 MFMA similarity tile + fused per-row top-6 ----------------
// grid (32, 64): 128x128 tile of S = hp_bf16[0:4096] . hp_bf16^T
// Staging: monotone global_load_dwordx4 -> regs -> XOR-swizzled ds_write_b128.
__global__ __launch_bounds__(256, 2) void k_simtop(const unsigned short* __restrict__ hp,
                                                   float* __restrict__ candv,
                                                   int* __restrict__ candi) {
    __shared__ char smem[39424];
    unsigned short* sA = (unsigned short*)smem;          // [128 rows][64 k] swizzled
    unsigned short* sB = sA + 128 * 64;
    float* sS = (float*)smem;                            // [128][65] score buffer (alias)
    float* mv = (float*)(smem + 33280);                  // [128][6] partner top-6 vals
    int*   mj = (int*)(smem + 33280 + 3072);             // [128][6] partner top-6 idx

    const int t = threadIdx.x;
    const int l = t & 63;
    const int w = t >> 6;
    const int l15 = l & 15, quad = l >> 4;
    const int wr = w >> 1, wc = w & 1;
    const int ri = blockIdx.x, ci = blockIdx.y;

    const unsigned short* Ab = hp + (size_t)(ri * 128) * D;
    const unsigned short* Bb = hp + (size_t)(ci * 128) * D;

    // staging: chunk c = p*256 + t (p=0..3): row=c>>3, src chunk=c&7
    // global read monotone in lane; LDS write position (c&7)^(row&7) [XOR swizzle]
    const unsigned short* pa[4];
    const unsigned short* pb[4];
    int wofs[4];                                         // swizzled LDS byte offset
    #pragma unroll
    for (int p = 0; p < 4; p++) {
        int c = p * 256 + t;
        int row = c >> 3, pos = c & 7;
        pa[p] = Ab + (size_t)row * D + pos * 8;
        pb[p] = Bb + (size_t)row * D + pos * 8;
        wofs[p] = row * 128 + ((pos ^ (row & 7)) * 16);
    }

    float4 ra[4], rb[4];
    #pragma unroll
    for (int p = 0; p < 4; p++) { ra[p] = *(const float4*)pa[p]; rb[p] = *(const float4*)pb[p]; }

    f32x4 acc[4][4];
    #pragma unroll
    for (int i = 0; i < 4; i++)
        #pragma unroll
        for (int j = 0; j < 4; j++) acc[i][j] = (f32x4){0.f, 0.f, 0.f, 0.f};

    // fragment LDS chunk offsets (lane-constant): source chunk q sits at pos q^(row&7)
    const int x7  = l15 & 7;
    const int ch0 = (quad ^ x7) * 16;
    const int ch1 = ((quad + 4) ^ x7) * 16;

    for (int kk = 0; kk < D; kk += 64) {
        __syncthreads();                                 // LDS readers of prev iter done
        #pragma unroll
        for (int p = 0; p < 4; p++) {
            *(float4*)(smem + wofs[p]) = ra[p];                       // sA region
            *(float4*)(smem + 128 * 128 + wofs[p]) = rb[p];           // sB region
        }
        __syncthreads();                                 // tile ready
        int kn = kk + 64;
        if (kn < D) {
            #pragma unroll
            for (int p = 0; p < 4; p++) {
                ra[p] = *(const float4*)(pa[p] + kn);
                rb[p] = *(const float4*)(pb[p] + kn);
            }
        }
        #pragma unroll
        for (int ks = 0; ks < 2; ks++) {
            const int ch = ks ? ch1 : ch0;
            bf16x8 af[4], bfr[4];
            #pragma unroll
            for (int mi = 0; mi < 4; mi++)
                af[mi] = *(const bf16x8*)((const char*)sA + (wr * 64 + mi * 16 + l15) * 128 + ch);
            #pragma unroll
            for (int ni = 0; ni < 4; ni++)
                bfr[ni] = *(const bf16x8*)((const char*)sB + (wc * 64 + ni * 16 + l15) * 128 + ch);
            #pragma unroll
            for (int mi = 0; mi < 4; mi++)
                #pragma unroll
                for (int ni = 0; ni < 4; ni++)
                    acc[mi][ni] = __builtin_amdgcn_mfma_f32_16x16x32_bf16(af[mi], bfr[ni], acc[mi][ni], 0, 0, 0);
        }
    }

    // epilogue: 2 dump phases of 64 cols; 256 threads scan 2-per-row (32 cols each)
    float bv[TOPK]; int bj[TOPK];
    #pragma unroll
    for (int s = 0; s < TOPK; s++) { bv[s] = -1e30f; bj[s] = 0x7fffffff; }

    const int srow = t & 127, scb = (t >> 7) * 32;
    #pragma unroll
    for (int h = 0; h < 2; h++) {
        __syncthreads();                                 // prior LDS reads done
        if (wc == h) {
            #pragma unroll
            for (int mi = 0; mi < 4; mi++)
                #pragma unroll
                for (int ni = 0; ni < 4; ni++) {
                    int colb = ni * 16 + l15;
                    int rowb = wr * 64 + mi * 16 + quad * 4;
                    f32x4 v = acc[mi][ni];
                    #pragma unroll
                    for (int r = 0; r < 4; r++) sS[(rowb + r) * 65 + colb] = v[r];
                }
        }
        __syncthreads();
        int jbase = ci * 128 + h * 64 + scb;
        for (int c = 0; c < 32; c++) {
            float v = sS[srow * 65 + scb + c];
            if (v > bv[TOPK - 1]) topk_insert(v, jbase + c, bv, bj);
        }
    }

    // merge the two half-row scanners
    __syncthreads();
    if (t >= 128) {
        #pragma unroll
        for (int s = 0; s < TOPK; s++) { mv[(t - 128) * TOPK + s] = bv[s]; mj[(t - 128) * TOPK + s] = bj[s]; }
    }
    __syncthreads();
    if (t < 128) {
        #pragma unroll
        for (int s0 = 0; s0 < TOPK; s0++) {
            float v = mv[t * TOPK + s0];
            if (v > bv[TOPK - 1]) topk_insert(v, mj[t * TOPK + s0], bv, bj);
        }
        size_t o = ((size_t)(ri * 128 + t) * NT + ci) * TOPK;
        #pragma unroll
        for (int s = 0; s < TOPK; s++) { candv[o + s] = bv[s]; candi[o + s] = bj[s]; }
    }
}

// ------- fused merge (wave-parallel) + sparse loss. One 64-thread block per row --
// lane = tile index: lane's 6 candidates are that tile's sorted top-6.
// 6 xor-merge rounds; low-lane list is the insertion base so ties keep smaller j.
__global__ __launch_bounds__(64) void k_mergeloss(const float* __restrict__ candv,
                                                  const int* __restrict__ candi,
                                                  const float* __restrict__ hcn,
                                                  const float* __restrict__ sq,
                                                  const int* __restrict__ labp,
                                                  float* __restrict__ partial) {
    int i = blockIdx.x;
    int lane = threadIdx.x;
    const float* cv = candv + ((size_t)i * NT + lane) * TOPK;
    const int*   cj = candi + ((size_t)i * NT + lane) * TOPK;
    float bv[TOPK]; int bj[TOPK];
    #pragma unroll
    for (int s = 0; s < TOPK; s++) { bv[s] = cv[s]; bj[s] = cj[s]; }

    #pragma unroll
    for (int off = 1; off < 64; off <<= 1) {
        float pv[TOPK]; int pj[TOPK];
        #pragma unroll
        for (int s = 0; s < TOPK; s++) {
            pv[s] = __shfl_xor(bv[s], off, 64);
            pj[s] = __shfl_xor(bj[s], off, 64);
        }
        bool ilow = (lane & off) == 0;
        float av[TOPK], iv[TOPK]; int aj[TOPK], ij[TOPK];
        #pragma unroll
        for (int s = 0; s < TOPK; s++) {
            av[s] = ilow ? bv[s] : pv[s];  aj[s] = ilow ? bj[s] : pj[s];
            iv[s] = ilow ? pv[s] : bv[s];  ij[s] = ilow ? pj[s] : bj[s];
        }
        #pragma unroll
        for (int s = 0; s < TOPK; s++)
            if (iv[s] > av[TOPK - 1]) topk_insert(iv[s], ij[s], av, aj);
        #pragma unroll
        for (int s = 0; s < TOPK; s++) { bv[s] = av[s]; bj[s] = aj[s]; }
    }

    // all lanes now hold the row's global top-6; rank 0 is self -> use ranks 1..5
    const float* hi = hcn + (size_t)i * D;
    float part = 0.f;
    int li = labp[i];
    #pragma unroll
    for (int s = 1; s <= KNB; s++) {
        int j = bj[s];
        if (j >= BC) continue;
        const float* hj = hcn + (size_t)j * D;
        float d = 0.f;
        #pragma unroll
        for (int m = 0; m < D / 64; m++) d += hi[lane + 64 * m] * hj[lane + 64 * m];
        #pragma unroll
        for (int off = 32; off; off >>= 1) d += __shfl_xor(d, off, 64);
        float d2 = fmaxf(sq[i] + sq[j] - 2.0f * d, 0.0f);
        float e = (li == labp[j]) ? 1.0f : -1.0f;
        part += e * d2;
    }
    if (lane == 0) partial[i] = part;
}

__global__ __launch_bounds__(256) void k_final(const float* __restrict__ partial,
                                               float* __restrict__ out) {
    __shared__ float red[256];
    int t = threadIdx.x;
    float s = 0.f;
    for (int i = t; i < BC; i += 256) s += partial[i];
    red[t] = s;
    __syncthreads();
    for (int off = 128; off; off >>= 1) {
        if (t < off) red[t] += red[t + off];
        __syncthreads();
    }
    if (t == 0) out[0] = 0.5f * red[0] / ((float)BC * (float)BC);
}

extern "C" void kernel_launch(void* const* d_in, const int* in_sizes, int n_in,
                              void* d_out, int out_size, void* d_ws, size_t ws_size,
                              hipStream_t stream) {
    const float* hc   = (const float*)d_in[0];  // hidden_current  (4096,768)
    const float* hp   = (const float*)d_in[1];  // hidden_previous (8192,768)
    const int*   labp = (const int*)d_in[3];    // labels_previous (8192,)
    float* out = (float*)d_out;

    // workspace layout (~38 MB)
    unsigned short* hpnb = (unsigned short*)d_ws;          // BP*D bf16
    float* hcn  = (float*)(hpnb + (size_t)BP * D);         // BC*D f32
    float* sq   = hcn + (size_t)BC * D;                    // BC
    float* candv = sq + BC;                                // BC*NT*TOPK
    int*   candi = (int*)(candv + (size_t)BC * NT * TOPK); // BC*NT*TOPK
    float* partial = (float*)(candi + (size_t)BC * NT * TOPK); // BC

    k_norm<<<dim3(BP + BC), dim3(256), 0, stream>>>(hp, hc, hpnb, hcn, sq);
    k_simtop<<<dim3(BC / 128, NT), dim3(256), 0, stream>>>(hpnb, candv, candi);
    k_mergeloss<<<dim3(BC), dim3(64), 0, stream>>>(candv, candi, hcn, sq, labp, partial);
    k_final<<<dim3(1), dim3(256), 0, stream>>>(partial, out);
}

// Round 6
// 185.473 us; speedup vs baseline: 12.0217x; 1.9996x over previous
//
#include <hip/hip_runtime.h>

#define BC 4096      // rows of hidden_current
#define BP 8192      // rows of hidden_previous
#define D  768
#define KNB 5
#define TOPK 6
#define NT (BP / 128)   // 64 column tiles of the similarity matrix

typedef __bf16 bf16x8 __attribute__((ext_vector_type(8)));
typedef float  f32x4  __attribute__((ext_vector_type(4)));

__device__ __forceinline__ unsigned short f2bf(float f) {
    unsigned int u = __float_as_uint(f);
    u += 0x7fffu + ((u >> 16) & 1u);          // round-to-nearest-even
    return (unsigned short)(u >> 16);
}

// Branchless insertion network, STATIC indices only. Strict >: ties keep the
// incumbent (earlier j), matching reference sequential j-ascending top_k.
__device__ __forceinline__ void topk_insert(float v, int j, float* bv, int* bj) {
    #pragma unroll
    for (int q = TOPK - 1; q >= 1; q--) {
        bool up   = v > bv[q - 1];
        bool here = (v > bv[q]) && !up;
        bv[q] = up ? bv[q - 1] : (here ? v : bv[q]);
        bj[q] = up ? bj[q - 1] : (here ? j : bj[q]);
    }
    if (v > bv[0]) { bv[0] = v; bj[0] = j; }
}

// ---------------- fused normalize: hp -> bf16 ranking copy, hc -> fp32 + sq ------
__global__ __launch_bounds__(256) void k_norm(const float* __restrict__ hp,
                                              const float* __restrict__ hc,
                                              unsigned short* __restrict__ hpnb,
                                              float* __restrict__ hcn,
                                              float* __restrict__ sqout) {
    int b = blockIdx.x;
    int t = threadIdx.x;
    bool isP = (b < BP);
    int row = isP ? b : (b - BP);
    const float* xr = (isP ? hp : hc) + (size_t)row * D;
    float v0 = xr[t], v1 = xr[t + 256], v2 = xr[t + 512];
    float s = v0 * v0 + v1 * v1 + v2 * v2;
    #pragma unroll
    for (int off = 32; off; off >>= 1) s += __shfl_xor(s, off, 64);
    __shared__ float wsum[4];
    if ((t & 63) == 0) wsum[t >> 6] = s;
    __syncthreads();
    float tot = wsum[0] + wsum[1] + wsum[2] + wsum[3];
    float rinv = 1.0f / fmaxf(sqrtf(tot), 1e-12f);
    if (isP) {
        unsigned short* yr = hpnb + (size_t)row * D;
        yr[t] = f2bf(v0 * rinv); yr[t + 256] = f2bf(v1 * rinv); yr[t + 512] = f2bf(v2 * rinv);
    } else {
        float* yr = hcn + (size_t)row * D;
        yr[t] = v0 * rinv; yr[t + 256] = v1 * rinv; yr[t + 512] = v2 * rinv;
        if (t == 0) sqout[row] = tot * rinv * rinv;
    }
}

// ---------------- bf16 MFMA similarity tile + fused per-row top-6 ----------------
// grid (32, 64): 128x128 tile of S = hp_bf16[0:4096] . hp_bf16^T
// Staging: monotone global_load_dwordx4 -> SCALAR regs -> XOR-swizzled ds_write.
// r5 lesson: float4 ARRAYS (ra[4]/rb[4]) were scratch-resident -> 800 MB/launch
// of scratch traffic. Named scalars cannot be indexed -> guaranteed registers.
__global__ __launch_bounds__(256, 2) void k_simtop(const unsigned short* __restrict__ hp,
                                                   float* __restrict__ candv,
                                                   int* __restrict__ candi) {
    __shared__ char smem[39424];
    unsigned short* sA = (unsigned short*)smem;          // [128 rows][64 k] swizzled
    unsigned short* sB = sA + 128 * 64;
    float* sS = (float*)smem;                            // [128][65] score buffer (alias)
    float* mv = (float*)(smem + 33280);                  // [128][6] partner top-6 vals
    int*   mj = (int*)(smem + 33280 + 3072);             // [128][6] partner top-6 idx

    const int t = threadIdx.x;
    const int l = t & 63;
    const int w = t >> 6;
    const int l15 = l & 15, quad = l >> 4;
    const int wr = w >> 1, wc = w & 1;
    const int ri = blockIdx.x, ci = blockIdx.y;

    const unsigned short* Ab = hp + (size_t)(ri * 128) * D;
    const unsigned short* Bb = hp + (size_t)(ci * 128) * D;

    // staging: chunk c = p*256 + t (p=0..3): row=c>>3, src chunk=c&7
    // global read monotone in lane; LDS write position (c&7)^(row&7) [XOR swizzle]
#define STAGE_INIT(P, PA, PB, WO)                                   \
    const unsigned short *PA, *PB; int WO;                          \
    { int c = (P) * 256 + t; int row_ = c >> 3, pos_ = c & 7;       \
      PA = Ab + (size_t)row_ * D + pos_ * 8;                        \
      PB = Bb + (size_t)row_ * D + pos_ * 8;                        \
      WO = row_ * 128 + ((pos_ ^ (row_ & 7)) * 16); }
    STAGE_INIT(0, pa0, pb0, wo0)
    STAGE_INIT(1, pa1, pb1, wo1)
    STAGE_INIT(2, pa2, pb2, wo2)
    STAGE_INIT(3, pa3, pb3, wo3)
#undef STAGE_INIT

    float4 ra0 = *(const float4*)pa0, ra1 = *(const float4*)pa1;
    float4 ra2 = *(const float4*)pa2, ra3 = *(const float4*)pa3;
    float4 rb0 = *(const float4*)pb0, rb1 = *(const float4*)pb1;
    float4 rb2 = *(const float4*)pb2, rb3 = *(const float4*)pb3;

    f32x4 acc[4][4];
    #pragma unroll
    for (int i = 0; i < 4; i++)
        #pragma unroll
        for (int j = 0; j < 4; j++) acc[i][j] = (f32x4){0.f, 0.f, 0.f, 0.f};

    // fragment LDS chunk offsets (lane-constant): source chunk q sits at pos q^(row&7)
    const int x7  = l15 & 7;
    const int ch0 = (quad ^ x7) * 16;
    const int ch1 = ((quad + 4) ^ x7) * 16;

    for (int kk = 0; kk < D; kk += 64) {
        __syncthreads();                                 // LDS readers of prev iter done
        *(float4*)(smem + wo0) = ra0;
        *(float4*)(smem + wo1) = ra1;
        *(float4*)(smem + wo2) = ra2;
        *(float4*)(smem + wo3) = ra3;
        *(float4*)(smem + 16384 + wo0) = rb0;
        *(float4*)(smem + 16384 + wo1) = rb1;
        *(float4*)(smem + 16384 + wo2) = rb2;
        *(float4*)(smem + 16384 + wo3) = rb3;
        __syncthreads();                                 // tile ready
        int kn = kk + 64;
        if (kn < D) {
            ra0 = *(const float4*)(pa0 + kn);
            ra1 = *(const float4*)(pa1 + kn);
            ra2 = *(const float4*)(pa2 + kn);
            ra3 = *(const float4*)(pa3 + kn);
            rb0 = *(const float4*)(pb0 + kn);
            rb1 = *(const float4*)(pb1 + kn);
            rb2 = *(const float4*)(pb2 + kn);
            rb3 = *(const float4*)(pb3 + kn);
        }
        #pragma unroll
        for (int ks = 0; ks < 2; ks++) {
            const int ch = ks ? ch1 : ch0;
            bf16x8 af[4], bfr[4];
            #pragma unroll
            for (int mi = 0; mi < 4; mi++)
                af[mi] = *(const bf16x8*)((const char*)sA + (wr * 64 + mi * 16 + l15) * 128 + ch);
            #pragma unroll
            for (int ni = 0; ni < 4; ni++)
                bfr[ni] = *(const bf16x8*)((const char*)sB + (wc * 64 + ni * 16 + l15) * 128 + ch);
            #pragma unroll
            for (int mi = 0; mi < 4; mi++)
                #pragma unroll
                for (int ni = 0; ni < 4; ni++)
                    acc[mi][ni] = __builtin_amdgcn_mfma_f32_16x16x32_bf16(af[mi], bfr[ni], acc[mi][ni], 0, 0, 0);
        }
    }

    // epilogue: 2 dump phases of 64 cols; 256 threads scan 2-per-row (32 cols each)
    float bv[TOPK]; int bj[TOPK];
    #pragma unroll
    for (int s = 0; s < TOPK; s++) { bv[s] = -1e30f; bj[s] = 0x7fffffff; }

    const int srow = t & 127, scb = (t >> 7) * 32;
    #pragma unroll
    for (int h = 0; h < 2; h++) {
        __syncthreads();                                 // prior LDS reads done
        if (wc == h) {
            #pragma unroll
            for (int mi = 0; mi < 4; mi++)
                #pragma unroll
                for (int ni = 0; ni < 4; ni++) {
                    int colb = ni * 16 + l15;
                    int rowb = wr * 64 + mi * 16 + quad * 4;
                    f32x4 v = acc[mi][ni];
                    #pragma unroll
                    for (int r = 0; r < 4; r++) sS[(rowb + r) * 65 + colb] = v[r];
                }
        }
        __syncthreads();
        int jbase = ci * 128 + h * 64 + scb;
        for (int c = 0; c < 32; c++) {
            float v = sS[srow * 65 + scb + c];
            if (v > bv[TOPK - 1]) topk_insert(v, jbase + c, bv, bj);
        }
    }

    // merge the two half-row scanners
    __syncthreads();
    if (t >= 128) {
        #pragma unroll
        for (int s = 0; s < TOPK; s++) { mv[(t - 128) * TOPK + s] = bv[s]; mj[(t - 128) * TOPK + s] = bj[s]; }
    }
    __syncthreads();
    if (t < 128) {
        #pragma unroll
        for (int s0 = 0; s0 < TOPK; s0++) {
            float v = mv[t * TOPK + s0];
            if (v > bv[TOPK - 1]) topk_insert(v, mj[t * TOPK + s0], bv, bj);
        }
        size_t o = ((size_t)(ri * 128 + t) * NT + ci) * TOPK;
        #pragma unroll
        for (int s = 0; s < TOPK; s++) { candv[o + s] = bv[s]; candi[o + s] = bj[s]; }
    }
}

// ------- fused merge (wave-parallel) + sparse loss. One 64-thread block per row --
// lane = tile index: lane's 6 candidates are that tile's sorted top-6.
// 6 xor-merge rounds; low-lane list is the insertion base so ties keep smaller j.
__global__ __launch_bounds__(64) void k_mergeloss(const float* __restrict__ candv,
                                                  const int* __restrict__ candi,
                                                  const float* __restrict__ hcn,
                                                  const float* __restrict__ sq,
                                                  const int* __restrict__ labp,
                                                  float* __restrict__ partial) {
    int i = blockIdx.x;
    int lane = threadIdx.x;
    const float* cv = candv + ((size_t)i * NT + lane) * TOPK;
    const int*   cj = candi + ((size_t)i * NT + lane) * TOPK;
    float bv[TOPK]; int bj[TOPK];
    #pragma unroll
    for (int s = 0; s < TOPK; s++) { bv[s] = cv[s]; bj[s] = cj[s]; }

    #pragma unroll
    for (int off = 1; off < 64; off <<= 1) {
        float pv[TOPK]; int pj[TOPK];
        #pragma unroll
        for (int s = 0; s < TOPK; s++) {
            pv[s] = __shfl_xor(bv[s], off, 64);
            pj[s] = __shfl_xor(bj[s], off, 64);
        }
        bool ilow = (lane & off) == 0;
        float av[TOPK], iv[TOPK]; int aj[TOPK], ij[TOPK];
        #pragma unroll
        for (int s = 0; s < TOPK; s++) {
            av[s] = ilow ? bv[s] : pv[s];  aj[s] = ilow ? bj[s] : pj[s];
            iv[s] = ilow ? pv[s] : bv[s];  ij[s] = ilow ? pj[s] : bj[s];
        }
        #pragma unroll
        for (int s = 0; s < TOPK; s++)
            if (iv[s] > av[TOPK - 1]) topk_insert(iv[s], ij[s], av, aj);
        #pragma unroll
        for (int s = 0; s < TOPK; s++) { bv[s] = av[s]; bj[s] = aj[s]; }
    }

    // all lanes now hold the row's global top-6; rank 0 is self -> use ranks 1..5
    const float* hi = hcn + (size_t)i * D;
    float part = 0.f;
    int li = labp[i];
    #pragma unroll
    for (int s = 1; s <= KNB; s++) {
        int j = bj[s];
        if (j >= BC) continue;
        const float* hj = hcn + (size_t)j * D;
        float d = 0.f;
        #pragma unroll
        for (int m = 0; m < D / 64; m++) d += hi[lane + 64 * m] * hj[lane + 64 * m];
        #pragma unroll
        for (int off = 32; off; off >>= 1) d += __shfl_xor(d, off, 64);
        float d2 = fmaxf(sq[i] + sq[j] - 2.0f * d, 0.0f);
        float e = (li == labp[j]) ? 1.0f : -1.0f;
        part += e * d2;
    }
    if (lane == 0) partial[i] = part;
}

__global__ __launch_bounds__(256) void k_final(const float* __restrict__ partial,
                                               float* __restrict__ out) {
    __shared__ float red[256];
    int t = threadIdx.x;
    float s = 0.f;
    for (int i = t; i < BC; i += 256) s += partial[i];
    red[t] = s;
    __syncthreads();
    for (int off = 128; off; off >>= 1) {
        if (t < off) red[t] += red[t + off];
        __syncthreads();
    }
    if (t == 0) out[0] = 0.5f * red[0] / ((float)BC * (float)BC);
}

extern "C" void kernel_launch(void* const* d_in, const int* in_sizes, int n_in,
                              void* d_out, int out_size, void* d_ws, size_t ws_size,
                              hipStream_t stream) {
    const float* hc   = (const float*)d_in[0];  // hidden_current  (4096,768)
    const float* hp   = (const float*)d_in[1];  // hidden_previous (8192,768)
    const int*   labp = (const int*)d_in[3];    // labels_previous (8192,)
    float* out = (float*)d_out;

    // workspace layout (~38 MB)
    unsigned short* hpnb = (unsigned short*)d_ws;          // BP*D bf16
    float* hcn  = (float*)(hpnb + (size_t)BP * D);         // BC*D f32
    float* sq   = hcn + (size_t)BC * D;                    // BC
    float* candv = sq + BC;                                // BC*NT*TOPK
    int*   candi = (int*)(candv + (size_t)BC * NT * TOPK); // BC*NT*TOPK
    float* partial = (float*)(candi + (size_t)BC * NT * TOPK); // BC

    k_norm<<<dim3(BP + BC), dim3(256), 0, stream>>>(hp, hc, hpnb, hcn, sq);
    k_simtop<<<dim3(BC / 128, NT), dim3(256), 0, stream>>>(hpnb, candv, candi);
    k_mergeloss<<<dim3(BC), dim3(64), 0, stream>>>(candv, candi, hcn, sq, labp, partial);
    k_final<<<dim3(1), dim3(256), 0, stream>>>(partial, out);
}